// Round 1
// baseline (454.841 us; speedup 1.0000x reference)
//
#include <hip/hip_runtime.h>
#include <math.h>

#define NN 100000
#define NE 1600000
#define DIM 64

// ---------------------------------------------------------------------------
// Kernel 0: u[k] = sum_j w_attn[j] * W[j][k]   (fold attention vec through fc)
// ---------------------------------------------------------------------------
__global__ void u_kernel(const float* __restrict__ W, const float* __restrict__ w_attn,
                         float* __restrict__ u) {
    int k = threadIdx.x;
    float s = 0.f;
#pragma unroll 8
    for (int j = 0; j < DIM; ++j) s += w_attn[j] * W[j * DIM + k];
    u[k] = s;
}

// ---------------------------------------------------------------------------
// Kernel 1: per-node projection  p = h @ W^T  and scalar  a = h . u
// Rows [0,NN) come from h_src -> p_src/a_src; rows [NN,2NN) from h_dst.
// Block = 256 threads handles 64 rows. 4x4 register blocking, b128 LDS reads.
// ---------------------------------------------------------------------------
__global__ __launch_bounds__(256) void proj_kernel(
    const float* __restrict__ h_src, const float* __restrict__ h_dst,
    const float* __restrict__ W, const float* __restrict__ u,
    float* __restrict__ p_src, float* __restrict__ p_dst,
    float* __restrict__ a_src, float* __restrict__ a_dst) {
    __shared__ __align__(16) float Wt[DIM * DIM];   // Wt[k*64 + j] = W[j][k]
    __shared__ __align__(16) float Ht[DIM * 68];    // Ht[k*68 + nl] (pad 68 vs bank conflicts)
    __shared__ float us[DIM];

    const int t = threadIdx.x;
    const int row0 = blockIdx.x * 64;

    // Stage W transposed. Lane j reads W[j][k] (stride-64 global; W is tiny,
    // L2-resident); LDS writes are consecutive-address -> conflict-free.
    {
        int j = t & 63;
        int kb = t >> 6;
#pragma unroll
        for (int r = 0; r < 16; ++r) {
            int k = r * 4 + kb;
            Wt[k * DIM + j] = W[j * DIM + k];
        }
    }
    if (t < DIM) us[t] = u[t];

    // Stage H tile transposed. Per wave: one full row per iteration,
    // coalesced 256B global read. LDS write is 8-way conflicted (acceptable).
    {
        int k = t & 63;
        int nb = t >> 6;
#pragma unroll
        for (int r = 0; r < 16; ++r) {
            int nl = r * 4 + nb;
            int row = row0 + nl;
            const float* hp = (row < NN) ? (h_src + (size_t)row * DIM)
                                         : (h_dst + (size_t)(row - NN) * DIM);
            Ht[k * 68 + nl] = hp[k];
        }
    }
    __syncthreads();

    // Main GEMM: thread computes 4 nodes x 4 channels.
    const int jg = (t & 15) * 4;
    const int ng = (t >> 4) * 4;
    float acc[4][4];
#pragma unroll
    for (int a = 0; a < 4; ++a)
#pragma unroll
        for (int b = 0; b < 4; ++b) acc[a][b] = 0.f;

#pragma unroll 4
    for (int k = 0; k < DIM; ++k) {
        const float4 wv = *(const float4*)(Wt + k * DIM + jg);
        const float4 hv = *(const float4*)(Ht + k * 68 + ng);
        const float wa[4] = {wv.x, wv.y, wv.z, wv.w};
        const float ha[4] = {hv.x, hv.y, hv.z, hv.w};
#pragma unroll
        for (int a = 0; a < 4; ++a)
#pragma unroll
            for (int b = 0; b < 4; ++b) acc[a][b] += ha[a] * wa[b];
    }

    // Store p: per node row, lanes (t&15) cover all 64 channels -> coalesced.
#pragma unroll
    for (int a = 0; a < 4; ++a) {
        int row = row0 + ng + a;
        float* pp = (row < NN) ? (p_src + (size_t)row * DIM)
                               : (p_dst + (size_t)(row - NN) * DIM);
        float4 v = make_float4(acc[a][0], acc[a][1], acc[a][2], acc[a][3]);
        *(float4*)(pp + jg) = v;
    }

    // Scalar attention projection a = h . u  (thread t < 64 -> node t)
    if (t < DIM) {
        int row = row0 + t;
        float s = 0.f;
#pragma unroll 8
        for (int k = 0; k < DIM; ++k) s += Ht[k * 68 + t] * us[k];
        if (row < NN) a_src[row] = s;
        else a_dst[row - NN] = s;
    }
}

// ---------------------------------------------------------------------------
// Kernel 2: per-edge score e = tanh(a_dst[dst] - a_src[src])
// ---------------------------------------------------------------------------
__global__ void edge_kernel(const float* __restrict__ a_src, const float* __restrict__ a_dst,
                            const int* __restrict__ src, const int* __restrict__ dst,
                            float* __restrict__ e) {
    int i = blockIdx.x * blockDim.x + threadIdx.x;
    if (i < NE) e[i] = tanhf(a_dst[dst[i]] - a_src[src[i]]);
}

// ---------------------------------------------------------------------------
// Kernel 3: per-node segment softmax + weighted aggregation + ELU.
// One wave per node (dst sorted => contiguous segment found by binary search).
// Lane = output channel; per-edge gather of p_src row is one coalesced 256B read.
// h_diff[n] = p_dst[n] - (sum_e w_e * p_src[src_e]) / s   (since sum alpha = 1)
// ---------------------------------------------------------------------------
__global__ __launch_bounds__(256) void agg_kernel(
    const float* __restrict__ p_src, const float* __restrict__ p_dst,
    const float* __restrict__ e, const int* __restrict__ src,
    const int* __restrict__ dst, float* __restrict__ out) {
    int wid = (blockIdx.x * 256 + threadIdx.x) >> 6;
    int lane = threadIdx.x & 63;
    if (wid >= NN) return;

    // lower_bound(dst, wid) and lower_bound(dst, wid+1) — wave-uniform.
    int lo = 0, hi = NE;
    while (lo < hi) {
        int mid = (lo + hi) >> 1;
        if (dst[mid] < wid) lo = mid + 1; else hi = mid;
    }
    int lo2 = lo, hi2 = NE;
    while (lo2 < hi2) {
        int mid = (lo2 + hi2) >> 1;
        if (dst[mid] < wid + 1) lo2 = mid + 1; else hi2 = mid;
    }
    const int beg = lo, end = lo2;
    const size_t obase = (size_t)wid * DIM + lane;

    if (end == beg) {           // empty segment: segment_sum = 0, elu(0) = 0
        out[obase] = 0.f;
        return;
    }

    // Phase 1: segment max (lanes strided over edges, then wave reduce).
    float m = -__builtin_inff();
    for (int i = beg + lane; i < end; i += 64) m = fmaxf(m, e[i]);
#pragma unroll
    for (int off = 32; off > 0; off >>= 1) m = fmaxf(m, __shfl_xor(m, off));

    // Phase 2: sequential over the segment; lane j accumulates channel j.
    float s = 0.f, acc = 0.f;
    for (int i = beg; i < end; ++i) {
        float w = __expf(e[i] - m);      // broadcast load of e[i]
        s += w;
        int sv = src[i];                 // broadcast load
        acc += w * p_src[(size_t)sv * DIM + lane];   // coalesced 256B gather
    }

    float hd = p_dst[obase] - acc / s;
    out[obase] = hd > 0.f ? hd : expm1f(hd);
}

// ---------------------------------------------------------------------------
extern "C" void kernel_launch(void* const* d_in, const int* in_sizes, int n_in,
                              void* d_out, int out_size, void* d_ws, size_t ws_size,
                              hipStream_t stream) {
    const float* h_src = (const float*)d_in[0];
    const float* h_dst = (const float*)d_in[1];
    const float* W     = (const float*)d_in[2];
    const float* w_at  = (const float*)d_in[3];
    const int*   src   = (const int*)d_in[4];
    const int*   dst   = (const int*)d_in[5];
    float* out = (float*)d_out;

    float* ws    = (float*)d_ws;
    float* u     = ws;                           // 64
    float* p_src = ws + 64;                      // NN*64
    float* p_dst = p_src + (size_t)NN * DIM;     // NN*64
    float* a_src = p_dst + (size_t)NN * DIM;     // NN
    float* a_dst = a_src + NN;                   // NN
    float* e     = a_dst + NN;                   // NE

    hipLaunchKernelGGL(u_kernel, dim3(1), dim3(64), 0, stream, W, w_at, u);
    hipLaunchKernelGGL(proj_kernel, dim3((2 * NN) / 64), dim3(256), 0, stream,
                       h_src, h_dst, W, u, p_src, p_dst, a_src, a_dst);
    hipLaunchKernelGGL(edge_kernel, dim3((NE + 255) / 256), dim3(256), 0, stream,
                       a_src, a_dst, src, dst, e);
    hipLaunchKernelGGL(agg_kernel, dim3((NN + 3) / 4), dim3(256), 0, stream,
                       p_src, p_dst, e, src, dst, out);
}

// Round 2
// 206.475 us; speedup vs baseline: 2.2029x; 2.2029x over previous
//
#include <hip/hip_runtime.h>
#include <math.h>

#define NN 100000
#define NE 1600000
#define DIM 64

// ---------------------------------------------------------------------------
// Kernel 1: per-node projection  p = h @ W^T  and scalar  a = p . w_attn
// Rows [0,NN) from h_src -> p_src/a_src; rows [NN,2NN) from h_dst.
// Block = 256 threads handles 64 rows. 4x4 register blocking.
// a = h.(W^T w_attn) = (h W^T).w_attn = p.w_attn  -> computed from the GEMM
// registers with a 16-lane shuffle reduce (no separate u pass needed).
// ---------------------------------------------------------------------------
#define WS 68   // padded LDS stride: (4k+j)%32 banks, float4-alignable (68*4=272=16*17)

__global__ __launch_bounds__(256) void proj_kernel(
    const float* __restrict__ h_src, const float* __restrict__ h_dst,
    const float* __restrict__ W, const float* __restrict__ w_attn,
    float* __restrict__ p_src, float* __restrict__ p_dst,
    float* __restrict__ a_src, float* __restrict__ a_dst) {
    __shared__ __align__(16) float Wt[DIM * WS];   // Wt[k*WS + j] = W[j][k]
    __shared__ __align__(16) float Ht[DIM * WS];   // Ht[k*WS + nl]
    __shared__ __align__(16) float was[DIM];

    const int t = threadIdx.x;
    const int row0 = blockIdx.x * 64;

    // Stage W transposed: coalesced global read, 8-way-conflict LDS write (cheap).
#pragma unroll
    for (int r = 0; r < 16; ++r) {
        int idx = r * 256 + t;          // linear over 64*64
        int j = idx >> 6, k = idx & 63;
        Wt[k * WS + j] = W[idx];
    }
    if (t < DIM) was[t] = w_attn[t];

    // Stage H tile transposed: per wave one full row per iter, coalesced 256B.
    {
        int k = t & 63;
        int nb = t >> 6;
#pragma unroll
        for (int r = 0; r < 16; ++r) {
            int nl = r * 4 + nb;
            int row = row0 + nl;
            const float* hp = (row < NN) ? (h_src + (size_t)row * DIM)
                                         : (h_dst + (size_t)(row - NN) * DIM);
            Ht[k * WS + nl] = hp[k];
        }
    }
    __syncthreads();

    // GEMM: thread computes 4 nodes x 4 channels.
    const int jg = (t & 15) * 4;
    const int ng = (t >> 4) * 4;
    float acc[4][4];
#pragma unroll
    for (int a = 0; a < 4; ++a)
#pragma unroll
        for (int b = 0; b < 4; ++b) acc[a][b] = 0.f;

#pragma unroll 4
    for (int k = 0; k < DIM; ++k) {
        const float4 wv = *(const float4*)(Wt + k * WS + jg);
        const float4 hv = *(const float4*)(Ht + k * WS + ng);
        const float wa[4] = {wv.x, wv.y, wv.z, wv.w};
        const float ha[4] = {hv.x, hv.y, hv.z, hv.w};
#pragma unroll
        for (int a = 0; a < 4; ++a)
#pragma unroll
            for (int b = 0; b < 4; ++b) acc[a][b] += ha[a] * wa[b];
    }

    // Store p (coalesced float4) and reduce a = p . w_attn across the 16 lanes
    // that hold one row (lanes (t>>4)*16 .. +15 are consecutive in the wave).
    const float4 wat4 = *(const float4*)(was + jg);
#pragma unroll
    for (int a = 0; a < 4; ++a) {
        int row = row0 + ng + a;
        float* pp = (row < NN) ? (p_src + (size_t)row * DIM)
                               : (p_dst + (size_t)(row - NN) * DIM);
        *(float4*)(pp + jg) = make_float4(acc[a][0], acc[a][1], acc[a][2], acc[a][3]);

        float pa = acc[a][0] * wat4.x + acc[a][1] * wat4.y +
                   acc[a][2] * wat4.z + acc[a][3] * wat4.w;
#pragma unroll
        for (int off = 8; off; off >>= 1) pa += __shfl_xor(pa, off);
        if ((t & 15) == 0) {
            if (row < NN) a_src[row] = pa;
            else a_dst[row - NN] = pa;
        }
    }
}

// ---------------------------------------------------------------------------
// Kernel 2: per-edge score e = tanh(a_dst[dst] - a_src[src]) + CSR row_ptr
// construction (dst is sorted: boundary where dst[i] != dst[i-1]).
// ---------------------------------------------------------------------------
__global__ void edge_kernel(const float* __restrict__ a_src, const float* __restrict__ a_dst,
                            const int* __restrict__ src, const int* __restrict__ dst,
                            float* __restrict__ e, int* __restrict__ row_ptr) {
    int i = blockIdx.x * blockDim.x + threadIdx.x;
    if (i >= NE) return;
    int d = dst[i];
    float x = a_dst[d] - a_src[src[i]];
    // tanh(x) = 1 - 2/(exp(2x)+1); saturates correctly at +-1 for |x| large
    e[i] = 1.f - 2.f / (__expf(2.f * x) + 1.f);

    int prev = (i == 0) ? -1 : dst[i - 1];
    for (int n = prev + 1; n <= d; ++n) row_ptr[n] = i;   // covers empty nodes
    if (i == NE - 1) {
        for (int n = d + 1; n <= NN; ++n) row_ptr[n] = NE; // tail + row_ptr[NN]
    }
}

// ---------------------------------------------------------------------------
// Kernel 3: per-node segment softmax + weighted aggregation + ELU.
// One wave per node; lane = output channel.
// h_diff[n] = p_dst[n] - (sum_e w_e * p_src[src_e]) / s   (since sum alpha = 1)
// e/src read coalesced across lanes (64 edges per load); per-edge (w,src)
// broadcast via readlane (SALU) -> inner loop is pure independent gathers.
// ---------------------------------------------------------------------------
__global__ __launch_bounds__(256) void agg_kernel(
    const float* __restrict__ p_src, const float* __restrict__ p_dst,
    const float* __restrict__ e, const int* __restrict__ src,
    const int* __restrict__ row_ptr, float* __restrict__ out) {
    int wid = (blockIdx.x * 256 + threadIdx.x) >> 6;
    int lane = threadIdx.x & 63;
    if (wid >= NN) return;

    const int beg = row_ptr[wid];
    const int end = row_ptr[wid + 1];
    const size_t obase = (size_t)wid * DIM + lane;

    if (end <= beg) {            // empty segment: segment_sum = 0, elu(0) = 0
        out[obase] = 0.f;
        return;
    }

    float pd = p_dst[obase];     // prefetch

    // Segment max (coalesced loads, lanes strided, then wave reduce).
    float m = -__builtin_inff();
    for (int c = beg + lane; c < end; c += 64) m = fmaxf(m, e[c]);
#pragma unroll
    for (int off = 32; off; off >>= 1) m = fmaxf(m, __shfl_xor(m, off));

    float s = 0.f, acc = 0.f;
    for (int cb = beg; cb < end; cb += 64) {
        int cd = end - cb; if (cd > 64) cd = 64;
        float w = 0.f; int sv = 0;
        if (lane < cd) {
            w = __expf(e[cb + lane] - m);   // coalesced
            sv = src[cb + lane];            // coalesced
        }
        float ws = w;
#pragma unroll
        for (int off = 32; off; off >>= 1) ws += __shfl_xor(ws, off);
        s += ws;

        int j = 0;
        for (; j + 8 <= cd; j += 8) {       // 8 independent gathers in flight
            float wj[8], v[8];
#pragma unroll
            for (int q = 0; q < 8; ++q) {
                int sq = __builtin_amdgcn_readlane(sv, j + q);
                wj[q] = __int_as_float(
                    __builtin_amdgcn_readlane(__float_as_int(w), j + q));
                v[q] = p_src[(size_t)sq * DIM + lane];   // coalesced 256B row
            }
#pragma unroll
            for (int q = 0; q < 8; ++q) acc += wj[q] * v[q];
        }
        for (; j < cd; ++j) {
            int sq = __builtin_amdgcn_readlane(sv, j);
            float wq = __int_as_float(
                __builtin_amdgcn_readlane(__float_as_int(w), j));
            acc += wq * p_src[(size_t)sq * DIM + lane];
        }
    }

    float hd = pd - acc / s;
    out[obase] = hd > 0.f ? hd : expm1f(hd);
}

// ---------------------------------------------------------------------------
extern "C" void kernel_launch(void* const* d_in, const int* in_sizes, int n_in,
                              void* d_out, int out_size, void* d_ws, size_t ws_size,
                              hipStream_t stream) {
    const float* h_src = (const float*)d_in[0];
    const float* h_dst = (const float*)d_in[1];
    const float* W     = (const float*)d_in[2];
    const float* w_at  = (const float*)d_in[3];
    const int*   src   = (const int*)d_in[4];
    const int*   dst   = (const int*)d_in[5];
    float* out = (float*)d_out;

    float* ws    = (float*)d_ws;
    float* p_src = ws;                           // NN*64
    float* p_dst = p_src + (size_t)NN * DIM;     // NN*64
    float* a_src = p_dst + (size_t)NN * DIM;     // NN
    float* a_dst = a_src + NN;                   // NN
    float* e     = a_dst + NN;                   // NE
    int*   row_ptr = (int*)(e + NE);             // NN+1

    hipLaunchKernelGGL(proj_kernel, dim3((2 * NN) / 64), dim3(256), 0, stream,
                       h_src, h_dst, W, w_at, p_src, p_dst, a_src, a_dst);
    hipLaunchKernelGGL(edge_kernel, dim3((NE + 255) / 256), dim3(256), 0, stream,
                       a_src, a_dst, src, dst, e, row_ptr);
    hipLaunchKernelGGL(agg_kernel, dim3((NN + 3) / 4), dim3(256), 0, stream,
                       p_src, p_dst, e, src, row_ptr, out);
}

// Round 3
// 194.039 us; speedup vs baseline: 2.3441x; 1.0641x over previous
//
#include <hip/hip_runtime.h>
#include <math.h>

#define NN 100000
#define NE 1600000
#define DIM 64

__device__ __forceinline__ unsigned f2bf_rn(float f) {
    unsigned u = __float_as_uint(f);
    u += 0x7fff + ((u >> 16) & 1);          // round-to-nearest-even
    return u >> 16;
}

// ---------------------------------------------------------------------------
// Kernel 1: per-node projection  p = h @ W^T  and scalar  a = p . w_attn
// Rows [0,NN) from h_src -> p_src (bf16 packed) / a_src; rows [NN,2NN) from
// h_dst -> p_dst (f32) / a_dst. Block = 256 threads handles 64 rows.
// ---------------------------------------------------------------------------
#define WS 68   // padded LDS stride

__global__ __launch_bounds__(256) void proj_kernel(
    const float* __restrict__ h_src, const float* __restrict__ h_dst,
    const float* __restrict__ W, const float* __restrict__ w_attn,
    unsigned* __restrict__ p_src16, float* __restrict__ p_dst,
    float* __restrict__ a_src, float* __restrict__ a_dst) {
    __shared__ __align__(16) float Wt[DIM * WS];   // Wt[k*WS + j] = W[j][k]
    __shared__ __align__(16) float Ht[DIM * WS];   // Ht[k*WS + nl]
    __shared__ __align__(16) float was[DIM];

    const int t = threadIdx.x;
    const int row0 = blockIdx.x * 64;

    // Stage W transposed (coalesced global read; LDS write conflicts are cheap).
#pragma unroll
    for (int r = 0; r < 16; ++r) {
        int idx = r * 256 + t;
        int j = idx >> 6, k = idx & 63;
        Wt[k * WS + j] = W[idx];
    }
    if (t < DIM) was[t] = w_attn[t];

    // Stage H tile transposed: per wave one full row per iter, coalesced 256B.
    {
        int k = t & 63;
        int nb = t >> 6;
#pragma unroll
        for (int r = 0; r < 16; ++r) {
            int nl = r * 4 + nb;
            int row = row0 + nl;
            const float* hp = (row < NN) ? (h_src + (size_t)row * DIM)
                                         : (h_dst + (size_t)(row - NN) * DIM);
            Ht[k * WS + nl] = hp[k];
        }
    }
    __syncthreads();

    // GEMM: thread computes 4 nodes x 4 channels.
    const int jg = (t & 15) * 4;
    const int ng = (t >> 4) * 4;
    float acc[4][4];
#pragma unroll
    for (int a = 0; a < 4; ++a)
#pragma unroll
        for (int b = 0; b < 4; ++b) acc[a][b] = 0.f;

#pragma unroll 4
    for (int k = 0; k < DIM; ++k) {
        const float4 wv = *(const float4*)(Wt + k * WS + jg);
        const float4 hv = *(const float4*)(Ht + k * WS + ng);
        const float wa[4] = {wv.x, wv.y, wv.z, wv.w};
        const float ha[4] = {hv.x, hv.y, hv.z, hv.w};
#pragma unroll
        for (int a = 0; a < 4; ++a)
#pragma unroll
            for (int b = 0; b < 4; ++b) acc[a][b] += ha[a] * wa[b];
    }

    const float4 wat4 = *(const float4*)(was + jg);
#pragma unroll
    for (int a = 0; a < 4; ++a) {
        int row = row0 + ng + a;
        if (row < NN) {
            // p_src: packed bf16, 2 channels per dword. 16 lanes x 8B = 128B row.
            uint2 pk;
            pk.x = f2bf_rn(acc[a][0]) | (f2bf_rn(acc[a][1]) << 16);
            pk.y = f2bf_rn(acc[a][2]) | (f2bf_rn(acc[a][3]) << 16);
            *(uint2*)(p_src16 + (size_t)row * 32 + (jg >> 1)) = pk;
        } else {
            float* pp = p_dst + (size_t)(row - NN) * DIM;
            *(float4*)(pp + jg) = make_float4(acc[a][0], acc[a][1], acc[a][2], acc[a][3]);
        }

        float pa = acc[a][0] * wat4.x + acc[a][1] * wat4.y +
                   acc[a][2] * wat4.z + acc[a][3] * wat4.w;
#pragma unroll
        for (int off = 8; off; off >>= 1) pa += __shfl_xor(pa, off);
        if ((t & 15) == 0) {
            if (row < NN) a_src[row] = pa;
            else a_dst[row - NN] = pa;
        }
    }
}

// ---------------------------------------------------------------------------
// Kernel 2: per-edge score e = tanh(a_dst[dst] - a_src[src]) + CSR row_ptr.
// ---------------------------------------------------------------------------
__global__ void edge_kernel(const float* __restrict__ a_src, const float* __restrict__ a_dst,
                            const int* __restrict__ src, const int* __restrict__ dst,
                            float* __restrict__ e, int* __restrict__ row_ptr) {
    int i = blockIdx.x * blockDim.x + threadIdx.x;
    if (i >= NE) return;
    int d = dst[i];
    float x = a_dst[d] - a_src[src[i]];
    e[i] = 1.f - 2.f / (__expf(2.f * x) + 1.f);   // tanh

    int prev = (i == 0) ? -1 : dst[i - 1];
    for (int n = prev + 1; n <= d; ++n) row_ptr[n] = i;
    if (i == NE - 1) {
        for (int n = d + 1; n <= NN; ++n) row_ptr[n] = NE;
    }
}

// ---------------------------------------------------------------------------
// Kernel 3: per-node segment softmax + weighted aggregation + ELU.
// One wave per node. bf16 p_src gathers: half-wave per edge, 2 channels/lane
// -> one dword load instruction fetches TWO edges' 128B rows.
// h_diff[n] = p_dst[n] - (sum_e w_e * p_src[src_e]) / s   (sum alpha = 1)
// ---------------------------------------------------------------------------
__global__ __launch_bounds__(256) void agg_kernel(
    const unsigned* __restrict__ p_src16, const float* __restrict__ p_dst,
    const float* __restrict__ e, const int* __restrict__ src,
    const int* __restrict__ row_ptr, float* __restrict__ out) {
    int wid = (blockIdx.x * 256 + threadIdx.x) >> 6;
    int lane = threadIdx.x & 63;
    if (wid >= NN) return;

    const int half = lane >> 5;          // which edge of the pair
    const int c = lane & 31;             // channel-pair index (ch 2c, 2c+1)
    const int beg = row_ptr[wid];
    const int end = row_ptr[wid + 1];
    const size_t ob2 = (size_t)wid * 32 + c;   // float2 index into p_dst/out

    if (end <= beg) {                    // empty segment: elu(0) = 0
        if (half == 0) ((float2*)out)[ob2] = make_float2(0.f, 0.f);
        return;
    }

    float2 pd = make_float2(0.f, 0.f);
    if (half == 0) pd = ((const float2*)p_dst)[ob2];   // prefetch

    // Segment max (coalesced, lanes strided, wave reduce).
    float m = -__builtin_inff();
    for (int i = beg + lane; i < end; i += 64) m = fmaxf(m, e[i]);
#pragma unroll
    for (int off = 32; off; off >>= 1) m = fmaxf(m, __shfl_xor(m, off));

    float s = 0.f, a0 = 0.f, a1 = 0.f;
    for (int cb = beg; cb < end; cb += 64) {
        int cd = end - cb; if (cd > 64) cd = 64;
        float w = 0.f; int sv = 0;
        if (lane < cd) {
            w = __expf(e[cb + lane] - m);   // coalesced
            sv = src[cb + lane];            // coalesced
        }
        float ws = w;
#pragma unroll
        for (int off = 32; off; off >>= 1) ws += __shfl_xor(ws, off);
        s += ws;

        int j = 0;
        for (; j + 8 <= cd; j += 8) {       // 4 loads (8 edges) in flight
            unsigned uu[4]; float wq[4];
#pragma unroll
            for (int q = 0; q < 4; ++q) {
                int jj = j + 2 * q;
                int s0 = __builtin_amdgcn_readlane(sv, jj);
                int s1 = __builtin_amdgcn_readlane(sv, jj + 1);
                float w0 = __int_as_float(__builtin_amdgcn_readlane(__float_as_int(w), jj));
                float w1 = __int_as_float(__builtin_amdgcn_readlane(__float_as_int(w), jj + 1));
                int sq = half ? s1 : s0;
                wq[q] = half ? w1 : w0;
                uu[q] = p_src16[(size_t)sq * 32 + c];
            }
#pragma unroll
            for (int q = 0; q < 4; ++q) {
                a0 += wq[q] * __uint_as_float(uu[q] << 16);
                a1 += wq[q] * __uint_as_float(uu[q] & 0xffff0000u);
            }
        }
        for (; j < cd; j += 2) {
            int s0 = __builtin_amdgcn_readlane(sv, j);
            int s1 = __builtin_amdgcn_readlane(sv, j + 1);   // w=0 there if j+1>=cd
            float w0 = __int_as_float(__builtin_amdgcn_readlane(__float_as_int(w), j));
            float w1 = __int_as_float(__builtin_amdgcn_readlane(__float_as_int(w), j + 1));
            int sq = half ? s1 : s0;
            float wqq = half ? w1 : w0;
            unsigned u = p_src16[(size_t)sq * 32 + c];
            a0 += wqq * __uint_as_float(u << 16);
            a1 += wqq * __uint_as_float(u & 0xffff0000u);
        }
    }

    // combine the two half-wave edge partitions
    a0 += __shfl_xor(a0, 32);
    a1 += __shfl_xor(a1, 32);

    if (half == 0) {
        float inv = 1.f / s;
        float h0 = pd.x - a0 * inv;
        float h1 = pd.y - a1 * inv;
        float2 o;
        o.x = h0 > 0.f ? h0 : expm1f(h0);
        o.y = h1 > 0.f ? h1 : expm1f(h1);
        ((float2*)out)[ob2] = o;
    }
}

// ---------------------------------------------------------------------------
extern "C" void kernel_launch(void* const* d_in, const int* in_sizes, int n_in,
                              void* d_out, int out_size, void* d_ws, size_t ws_size,
                              hipStream_t stream) {
    const float* h_src = (const float*)d_in[0];
    const float* h_dst = (const float*)d_in[1];
    const float* W     = (const float*)d_in[2];
    const float* w_at  = (const float*)d_in[3];
    const int*   src   = (const int*)d_in[4];
    const int*   dst   = (const int*)d_in[5];
    float* out = (float*)d_out;

    char* ws = (char*)d_ws;
    unsigned* p_src16 = (unsigned*)ws;                       // NN*32 dwords (12.8 MB)
    float* p_dst = (float*)(ws + (size_t)NN * 32 * 4);       // NN*64 floats (25.6 MB)
    float* a_src = p_dst + (size_t)NN * DIM;                 // NN
    float* a_dst = a_src + NN;                               // NN
    float* e     = a_dst + NN;                               // NE
    int*   row_ptr = (int*)(e + NE);                         // NN+1

    hipLaunchKernelGGL(proj_kernel, dim3((2 * NN) / 64), dim3(256), 0, stream,
                       h_src, h_dst, W, w_at, p_src16, p_dst, a_src, a_dst);
    hipLaunchKernelGGL(edge_kernel, dim3((NE + 255) / 256), dim3(256), 0, stream,
                       a_src, a_dst, src, dst, e, row_ptr);
    hipLaunchKernelGGL(agg_kernel, dim3((NN + 3) / 4), dim3(256), 0, stream,
                       p_src16, p_dst, e, src, row_ptr, out);
}

// Round 4
// 187.852 us; speedup vs baseline: 2.4213x; 1.0329x over previous
//
#include <hip/hip_runtime.h>
#include <math.h>

#define NN 100000
#define NE 1600000
#define DIM 64

__device__ __forceinline__ unsigned f2bf_rn(float f) {
    unsigned u = __float_as_uint(f);
    u += 0x7fff + ((u >> 16) & 1);          // round-to-nearest-even
    return u >> 16;
}

// ---------------------------------------------------------------------------
// Kernel 1: per-node projection  p = h @ W^T  and scalar  a = p . w_attn
// Rows [0,NN) from h_src -> p_src (bf16 packed) / a_src; rows [NN,2NN) from
// h_dst -> p_dst (f32) / a_dst. Block = 256 threads handles 64 rows.
// ---------------------------------------------------------------------------
#define WS 68   // padded LDS stride (keeps 16B alignment: 68*4=272)

__global__ __launch_bounds__(256) void proj_kernel(
    const float* __restrict__ h_src, const float* __restrict__ h_dst,
    const float* __restrict__ W, const float* __restrict__ w_attn,
    unsigned* __restrict__ p_src16, float* __restrict__ p_dst,
    float* __restrict__ a_src, float* __restrict__ a_dst) {
    __shared__ __align__(16) float Wt[DIM * WS];   // Wt[k*WS + j] = W[j][k]
    __shared__ __align__(16) float Ht[DIM * WS];   // Ht[k*WS + nl]
    __shared__ __align__(16) float was[DIM];

    const int t = threadIdx.x;
    const int row0 = blockIdx.x * 64;

    // Stage W transposed (coalesced global read; LDS write conflicts are cheap).
#pragma unroll
    for (int r = 0; r < 16; ++r) {
        int idx = r * 256 + t;
        int j = idx >> 6, k = idx & 63;
        Wt[k * WS + j] = W[idx];
    }
    if (t < DIM) was[t] = w_attn[t];

    // Stage H tile transposed: per wave one full row per iter, coalesced 256B.
    {
        int k = t & 63;
        int nb = t >> 6;
#pragma unroll
        for (int r = 0; r < 16; ++r) {
            int nl = r * 4 + nb;
            int row = row0 + nl;
            const float* hp = (row < NN) ? (h_src + (size_t)row * DIM)
                                         : (h_dst + (size_t)(row - NN) * DIM);
            Ht[k * WS + nl] = hp[k];
        }
    }
    __syncthreads();

    // GEMM: thread computes 4 nodes x 4 channels.
    const int jg = (t & 15) * 4;
    const int ng = (t >> 4) * 4;
    float acc[4][4];
#pragma unroll
    for (int a = 0; a < 4; ++a)
#pragma unroll
        for (int b = 0; b < 4; ++b) acc[a][b] = 0.f;

#pragma unroll 4
    for (int k = 0; k < DIM; ++k) {
        const float4 wv = *(const float4*)(Wt + k * WS + jg);
        const float4 hv = *(const float4*)(Ht + k * WS + ng);
        const float wa[4] = {wv.x, wv.y, wv.z, wv.w};
        const float ha[4] = {hv.x, hv.y, hv.z, hv.w};
#pragma unroll
        for (int a = 0; a < 4; ++a)
#pragma unroll
            for (int b = 0; b < 4; ++b) acc[a][b] += ha[a] * wa[b];
    }

    const float4 wat4 = *(const float4*)(was + jg);
#pragma unroll
    for (int a = 0; a < 4; ++a) {
        int row = row0 + ng + a;
        if (row < NN) {
            // p_src: packed bf16, 2 channels per dword. 16 lanes x 8B = 128B row.
            uint2 pk;
            pk.x = f2bf_rn(acc[a][0]) | (f2bf_rn(acc[a][1]) << 16);
            pk.y = f2bf_rn(acc[a][2]) | (f2bf_rn(acc[a][3]) << 16);
            *(uint2*)(p_src16 + (size_t)row * 32 + (jg >> 1)) = pk;
        } else {
            float* pp = p_dst + (size_t)(row - NN) * DIM;
            *(float4*)(pp + jg) = make_float4(acc[a][0], acc[a][1], acc[a][2], acc[a][3]);
        }

        float pa = acc[a][0] * wat4.x + acc[a][1] * wat4.y +
                   acc[a][2] * wat4.z + acc[a][3] * wat4.w;
#pragma unroll
        for (int off = 8; off; off >>= 1) pa += __shfl_xor(pa, off);
        if ((t & 15) == 0) {
            if (row < NN) a_src[row] = pa;
            else a_dst[row - NN] = pa;
        }
    }
}

// ---------------------------------------------------------------------------
// Kernel 2: per-edge softmax numerator w = exp(tanh(a_dst[dst]-a_src[src])),
// packed with src index; plus CSR row_ptr (dst sorted).
// No max-subtraction needed: tanh in [-1,1] => exp(e) in [0.37, 2.72], and
// exp(e)/sum exp(e) == exp(e-m)/sum exp(e-m) exactly.
// ---------------------------------------------------------------------------
__global__ void edge_kernel(const float* __restrict__ a_src, const float* __restrict__ a_dst,
                            const int* __restrict__ src, const int* __restrict__ dst,
                            uint2* __restrict__ pack, int* __restrict__ row_ptr) {
    int i = blockIdx.x * blockDim.x + threadIdx.x;
    if (i >= NE) return;
    int d = dst[i];
    int sv = src[i];
    float x = a_dst[d] - a_src[sv];
    float t = 1.f - 2.f / (__expf(2.f * x) + 1.f);   // tanh
    float w = __expf(t);
    pack[i] = make_uint2(__float_as_uint(w), (unsigned)sv);

    int prev = (i == 0) ? -1 : dst[i - 1];
    for (int n = prev + 1; n <= d; ++n) row_ptr[n] = i;
    if (i == NE - 1) {
        for (int n = d + 1; n <= NN; ++n) row_ptr[n] = NE;
    }
}

// ---------------------------------------------------------------------------
// Kernel 3: per-node aggregation + ELU. One wave per node.
// Eighth-wave per edge: sub = lane>>3 picks the edge in an 8-group, chunk =
// lane&7 picks a 16B piece of the 128B bf16 row -> ONE global_load_dwordx4
// instruction gathers 8 edges' rows. (w,src) pairs staged in wave-private LDS
// and re-read broadcast (ds_read_b64, off the VALU critical path).
// h_diff[n] = p_dst[n] - (sum_e w_e * p_src[src_e]) / s   (sum alpha = 1)
// ---------------------------------------------------------------------------
__global__ __launch_bounds__(256) void agg_kernel(
    const uint4* __restrict__ p_src16,   // NN x 8 uint4  (64 bf16 per row)
    const float4* __restrict__ p_dst4,   // NN x 16 float4
    const uint2* __restrict__ pack,      // NE x (w bits, src)
    const int* __restrict__ row_ptr, float4* __restrict__ out4) {
    __shared__ uint2 buf[4][64];
    const int wv = threadIdx.x >> 6;
    const int lane = threadIdx.x & 63;
    const int wid = blockIdx.x * 4 + wv;
    if (wid >= NN) return;

    const int sub = lane >> 3;      // which edge of the 8-group
    const int chunk = lane & 7;     // which 16B chunk of the row
    const size_t ob = (size_t)wid * 16 + chunk * 2;

    const int beg = row_ptr[wid];
    const int end = row_ptr[wid + 1];

    if (end <= beg) {               // empty segment: elu(0) = 0
        if (sub == 0) {
            out4[ob]     = make_float4(0.f, 0.f, 0.f, 0.f);
            out4[ob + 1] = make_float4(0.f, 0.f, 0.f, 0.f);
        }
        return;
    }

    // prefetch p_dst chunks (redundant across sub; only sub==0 consumed)
    float4 pd0 = p_dst4[ob];
    float4 pd1 = p_dst4[ob + 1];

    float sAcc = 0.f;
    float acc[8];
#pragma unroll
    for (int q = 0; q < 8; ++q) acc[q] = 0.f;

    uint2* bufw = buf[wv];

    for (int cb = beg; cb < end; cb += 64) {
        int cd = end - cb; if (cd > 64) cd = 64;
        uint2 pk = make_uint2(0u, 0u);
        if (lane < cd) pk = pack[cb + lane];    // coalesced 8B/lane
        bufw[lane] = pk;                        // wave-private; lgkm wait auto
        sAcc += __uint_as_float(pk.x);

        for (int j = 0; j < cd; j += 16) {      // 16 edges per iter, 2 loads in flight
            uint2 e0 = bufw[j + sub];
            uint2 e1 = bufw[j + 8 + sub];       // zeros beyond cd (buf zero-filled)
            uint4 r0 = p_src16[(unsigned)(e0.y * 8u + chunk)];
            uint4 r1 = p_src16[(unsigned)(e1.y * 8u + chunk)];
            float w0 = __uint_as_float(e0.x);
            float w1 = __uint_as_float(e1.x);
            acc[0] += w0 * __uint_as_float(r0.x << 16);
            acc[1] += w0 * __uint_as_float(r0.x & 0xffff0000u);
            acc[2] += w0 * __uint_as_float(r0.y << 16);
            acc[3] += w0 * __uint_as_float(r0.y & 0xffff0000u);
            acc[4] += w0 * __uint_as_float(r0.z << 16);
            acc[5] += w0 * __uint_as_float(r0.z & 0xffff0000u);
            acc[6] += w0 * __uint_as_float(r0.w << 16);
            acc[7] += w0 * __uint_as_float(r0.w & 0xffff0000u);
            acc[0] += w1 * __uint_as_float(r1.x << 16);
            acc[1] += w1 * __uint_as_float(r1.x & 0xffff0000u);
            acc[2] += w1 * __uint_as_float(r1.y << 16);
            acc[3] += w1 * __uint_as_float(r1.y & 0xffff0000u);
            acc[4] += w1 * __uint_as_float(r1.z << 16);
            acc[5] += w1 * __uint_as_float(r1.z & 0xffff0000u);
            acc[6] += w1 * __uint_as_float(r1.w << 16);
            acc[7] += w1 * __uint_as_float(r1.w & 0xffff0000u);
        }
    }

    // reduce s over the wave; reduce acc over the 8 sub-groups
#pragma unroll
    for (int off = 32; off; off >>= 1) sAcc += __shfl_xor(sAcc, off);
#pragma unroll
    for (int q = 0; q < 8; ++q) {
        acc[q] += __shfl_xor(acc[q], 8);
        acc[q] += __shfl_xor(acc[q], 16);
        acc[q] += __shfl_xor(acc[q], 32);
    }

    if (sub == 0) {
        float inv = 1.f / sAcc;
        float h0 = pd0.x - acc[0] * inv;
        float h1 = pd0.y - acc[1] * inv;
        float h2 = pd0.z - acc[2] * inv;
        float h3 = pd0.w - acc[3] * inv;
        float h4 = pd1.x - acc[4] * inv;
        float h5 = pd1.y - acc[5] * inv;
        float h6 = pd1.z - acc[6] * inv;
        float h7 = pd1.w - acc[7] * inv;
        float4 o0, o1;
        o0.x = h0 > 0.f ? h0 : expm1f(h0);
        o0.y = h1 > 0.f ? h1 : expm1f(h1);
        o0.z = h2 > 0.f ? h2 : expm1f(h2);
        o0.w = h3 > 0.f ? h3 : expm1f(h3);
        o1.x = h4 > 0.f ? h4 : expm1f(h4);
        o1.y = h5 > 0.f ? h5 : expm1f(h5);
        o1.z = h6 > 0.f ? h6 : expm1f(h6);
        o1.w = h7 > 0.f ? h7 : expm1f(h7);
        out4[ob]     = o0;
        out4[ob + 1] = o1;
    }
}

// ---------------------------------------------------------------------------
extern "C" void kernel_launch(void* const* d_in, const int* in_sizes, int n_in,
                              void* d_out, int out_size, void* d_ws, size_t ws_size,
                              hipStream_t stream) {
    const float* h_src = (const float*)d_in[0];
    const float* h_dst = (const float*)d_in[1];
    const float* W     = (const float*)d_in[2];
    const float* w_at  = (const float*)d_in[3];
    const int*   src   = (const int*)d_in[4];
    const int*   dst   = (const int*)d_in[5];

    char* ws = (char*)d_ws;
    unsigned* p_src16 = (unsigned*)ws;                          // 12.8 MB
    float* p_dst = (float*)(ws + (size_t)NN * 32 * 4);          // 25.6 MB
    float* a_src = p_dst + (size_t)NN * DIM;                    // 0.4 MB
    float* a_dst = a_src + NN;                                  // 0.4 MB
    uint2* pack  = (uint2*)(a_dst + NN);                        // 12.8 MB (16B-aligned offset)
    int*   row_ptr = (int*)(pack + NE);                         // NN+1

    hipLaunchKernelGGL(proj_kernel, dim3((2 * NN) / 64), dim3(256), 0, stream,
                       h_src, h_dst, W, w_at, p_src16, p_dst, a_src, a_dst);
    hipLaunchKernelGGL(edge_kernel, dim3((NE + 255) / 256), dim3(256), 0, stream,
                       a_src, a_dst, src, dst, pack, row_ptr);
    hipLaunchKernelGGL(agg_kernel, dim3((NN + 3) / 4), dim3(256), 0, stream,
                       (const uint4*)p_src16, (const float4*)p_dst, pack, row_ptr,
                       (float4*)d_out);
}

// Round 6
// 175.983 us; speedup vs baseline: 2.5846x; 1.0674x over previous
//
#include <hip/hip_runtime.h>
#include <hip/hip_fp16.h>
#include <math.h>

#define NN 100000
#define NE 1600000
#define DIM 64

__device__ __forceinline__ __half2 u2h2(unsigned u) { __half2 h; __builtin_memcpy(&h, &u, 4); return h; }
__device__ __forceinline__ unsigned h22u(__half2 h) { unsigned u; __builtin_memcpy(&u, &h, 4); return u; }
__device__ __forceinline__ unsigned pk_f16(float a, float b) {
    auto h = __builtin_amdgcn_cvt_pkrtz(a, b);   // __fp16 ext_vector(2), one v_cvt_pkrtz
    unsigned u; __builtin_memcpy(&u, &h, 4); return u;
}

// ---------------------------------------------------------------------------
// Kernel 1: per-node projection  p = h @ W^T  (packed f16, rows [0,2NN)) and
// scalar a = p . w_attn. Rows [0,NN) = h_src, [NN,2NN) = h_dst.
// Block = 256 threads handles 64 rows; 4x4 register blocking.
// ---------------------------------------------------------------------------
#define WS 68   // padded LDS stride

__global__ __launch_bounds__(256) void proj_kernel(
    const float* __restrict__ h_src, const float* __restrict__ h_dst,
    const float* __restrict__ W, const float* __restrict__ w_attn,
    unsigned* __restrict__ p16, float* __restrict__ a_src, float* __restrict__ a_dst) {
    __shared__ __align__(16) float Wt[DIM * WS];
    __shared__ __align__(16) float Ht[DIM * WS];
    __shared__ __align__(16) float was[DIM];

    const int t = threadIdx.x;
    const int row0 = blockIdx.x * 64;

#pragma unroll
    for (int r = 0; r < 16; ++r) {
        int idx = r * 256 + t;
        int j = idx >> 6, k = idx & 63;
        Wt[k * WS + j] = W[idx];
    }
    if (t < DIM) was[t] = w_attn[t];

    {
        int k = t & 63;
        int nb = t >> 6;
#pragma unroll
        for (int r = 0; r < 16; ++r) {
            int nl = r * 4 + nb;
            int row = row0 + nl;
            const float* hp = (row < NN) ? (h_src + (size_t)row * DIM)
                                         : (h_dst + (size_t)(row - NN) * DIM);
            Ht[k * WS + nl] = hp[k];
        }
    }
    __syncthreads();

    const int jg = (t & 15) * 4;
    const int ng = (t >> 4) * 4;
    float acc[4][4];
#pragma unroll
    for (int a = 0; a < 4; ++a)
#pragma unroll
        for (int b = 0; b < 4; ++b) acc[a][b] = 0.f;

#pragma unroll 4
    for (int k = 0; k < DIM; ++k) {
        const float4 wv = *(const float4*)(Wt + k * WS + jg);
        const float4 hv = *(const float4*)(Ht + k * WS + ng);
        const float wa[4] = {wv.x, wv.y, wv.z, wv.w};
        const float ha[4] = {hv.x, hv.y, hv.z, hv.w};
#pragma unroll
        for (int a = 0; a < 4; ++a)
#pragma unroll
            for (int b = 0; b < 4; ++b) acc[a][b] += ha[a] * wa[b];
    }

    const float4 wat4 = *(const float4*)(was + jg);
#pragma unroll
    for (int a = 0; a < 4; ++a) {
        int row = row0 + ng + a;
        uint2 pk;
        pk.x = pk_f16(acc[a][0], acc[a][1]);
        pk.y = pk_f16(acc[a][2], acc[a][3]);
        *(uint2*)(p16 + (size_t)row * 32 + (jg >> 1)) = pk;

        float pa = acc[a][0] * wat4.x + acc[a][1] * wat4.y +
                   acc[a][2] * wat4.z + acc[a][3] * wat4.w;
#pragma unroll
        for (int off = 8; off; off >>= 1) pa += __shfl_xor(pa, off);
        if ((t & 15) == 0) {
            if (row < NN) a_src[row] = pa;
            else a_dst[row - NN] = pa;
        }
    }
}

// ---------------------------------------------------------------------------
// Kernel 2: CSR row_ptr from sorted dst (boundary scan).
// ---------------------------------------------------------------------------
__global__ void rowptr_kernel(const int* __restrict__ dst, int* __restrict__ row_ptr) {
    int i = blockIdx.x * blockDim.x + threadIdx.x;
    if (i >= NE) return;
    int d = dst[i];
    int prev = (i == 0) ? -1 : dst[i - 1];
    for (int n = prev + 1; n <= d; ++n) row_ptr[n] = i;
    if (i == NE - 1) {
        for (int n = d + 1; n <= NN; ++n) row_ptr[n] = NE;
    }
}

// ---------------------------------------------------------------------------
// Kernel 3: fused edge-score + segment softmax + aggregation + ELU.
// One wave per node. Within a segment dst==wid, so
//   w = exp(tanh(a_dst[wid] - a_src[src]))   (no max shift: tanh in [-1,1])
// computed inline at staging (a_src is 400KB -> L2 resident). Eighth-wave per
// edge: sub=lane>>3 picks edge, chunk=lane&7 picks a 16B piece of the 128B f16
// row -> one dwordx4 gathers 8 edges' rows. Per-edge (w,w) half2 + pre-scaled
// byte offset staged in wave-private LDS. Inner MAC: __hfma2 (2 ch/inst).
// h_diff[n] = p_dst[n] - (sum_e w_e * p_src[src_e]) / s   (sum alpha = 1)
// ---------------------------------------------------------------------------
__global__ __launch_bounds__(256) void agg_kernel(
    const char* __restrict__ p16base,    // rows of 128B f16; [0,NN)=src, [NN,2NN)=dst
    const float* __restrict__ a_src, const float* __restrict__ a_dst,
    const int* __restrict__ src, const int* __restrict__ row_ptr,
    float4* __restrict__ out4) {
    __shared__ uint2 buf[4][64];
    const int wv = threadIdx.x >> 6;
    const int lane = threadIdx.x & 63;
    const int wid = blockIdx.x * 4 + wv;
    if (wid >= NN) return;

    const int sub = lane >> 3;
    const int chunk = lane & 7;
    const size_t ob = (size_t)wid * 16 + chunk * 2;

    const int beg = row_ptr[wid];
    const int end = row_ptr[wid + 1];

    if (end <= beg) {
        if (sub == 0) {
            out4[ob]     = make_float4(0.f, 0.f, 0.f, 0.f);
            out4[ob + 1] = make_float4(0.f, 0.f, 0.f, 0.f);
        }
        return;
    }

    const float ad = a_dst[wid];                       // wave-uniform
    const char* pbase = p16base + (size_t)chunk * 16;  // lane-invariant across loop

    float sAcc = 0.f;
    __half2 acc[4];
#pragma unroll
    for (int q = 0; q < 4; ++q) acc[q] = u2h2(0u);

    uint2* bufw = buf[wv];

    for (int cb = beg; cb < end; cb += 64) {
        int cd = end - cb; if (cd > 64) cd = 64;
        uint2 pk = make_uint2(0u, 0u);
        if (lane < cd) {
            int sv = src[cb + lane];                   // coalesced
            float x = ad - a_src[sv];                  // 4B gather, L2-resident
            float th = 1.f - 2.f / (__expf(2.f * x) + 1.f);   // tanh
            float w = __expf(th);
            sAcc += w;
            pk.x = pk_f16(w, w);                       // (w,w) half2
            pk.y = (unsigned)sv * 128u;                // pre-scaled byte offset
        }
        bufw[lane] = pk;

        for (int j = 0; j < cd; j += 16) {             // 16 edges/iter, 2 loads in flight
            uint2 e0 = bufw[j + sub];
            uint2 e1 = bufw[j + 8 + sub];
            uint4 r0 = *(const uint4*)(pbase + e0.y);
            uint4 r1 = *(const uint4*)(pbase + e1.y);
            __half2 w0 = u2h2(e0.x), w1 = u2h2(e1.x);
            acc[0] = __hfma2(w0, u2h2(r0.x), acc[0]);
            acc[1] = __hfma2(w0, u2h2(r0.y), acc[1]);
            acc[2] = __hfma2(w0, u2h2(r0.z), acc[2]);
            acc[3] = __hfma2(w0, u2h2(r0.w), acc[3]);
            acc[0] = __hfma2(w1, u2h2(r1.x), acc[0]);
            acc[1] = __hfma2(w1, u2h2(r1.y), acc[1]);
            acc[2] = __hfma2(w1, u2h2(r1.z), acc[2]);
            acc[3] = __hfma2(w1, u2h2(r1.w), acc[3]);
        }
    }

    // reduce s over wave; reduce acc across the 8 sub-groups
#pragma unroll
    for (int off = 32; off; off >>= 1) sAcc += __shfl_xor(sAcc, off);
#pragma unroll
    for (int off = 8; off <= 32; off <<= 1) {
#pragma unroll
        for (int q = 0; q < 4; ++q)
            acc[q] = __hadd2(acc[q], u2h2(__shfl_xor(h22u(acc[q]), off)));
    }

    if (sub == 0) {
        const uint4 pdu = *(const uint4*)(p16base + ((size_t)(NN + wid)) * 128 + (size_t)chunk * 16);
        const unsigned pw[4] = {pdu.x, pdu.y, pdu.z, pdu.w};
        const float inv = 1.f / sAcc;
        float o[8];
#pragma unroll
        for (int q = 0; q < 4; ++q) {
            float2 pf = __half22float2(u2h2(pw[q]));
            float2 af = __half22float2(acc[q]);
            float h0 = pf.x - af.x * inv;
            float h1 = pf.y - af.y * inv;
            o[2 * q]     = h0 > 0.f ? h0 : __expf(h0) - 1.f;
            o[2 * q + 1] = h1 > 0.f ? h1 : __expf(h1) - 1.f;
        }
        out4[ob]     = make_float4(o[0], o[1], o[2], o[3]);
        out4[ob + 1] = make_float4(o[4], o[5], o[6], o[7]);
    }
}

// ---------------------------------------------------------------------------
extern "C" void kernel_launch(void* const* d_in, const int* in_sizes, int n_in,
                              void* d_out, int out_size, void* d_ws, size_t ws_size,
                              hipStream_t stream) {
    const float* h_src = (const float*)d_in[0];
    const float* h_dst = (const float*)d_in[1];
    const float* W     = (const float*)d_in[2];
    const float* w_at  = (const float*)d_in[3];
    const int*   src   = (const int*)d_in[4];
    const int*   dst   = (const int*)d_in[5];

    char* ws = (char*)d_ws;
    unsigned* p16 = (unsigned*)ws;                        // 2NN*32 dwords = 25.6 MB
    float* a_src = (float*)(ws + (size_t)2 * NN * 32 * 4);
    float* a_dst = a_src + NN;
    int* row_ptr = (int*)(a_dst + NN);                    // NN+1

    hipLaunchKernelGGL(proj_kernel, dim3((2 * NN) / 64), dim3(256), 0, stream,
                       h_src, h_dst, W, w_at, p16, a_src, a_dst);
    hipLaunchKernelGGL(rowptr_kernel, dim3((NE + 255) / 256), dim3(256), 0, stream,
                       dst, row_ptr);
    hipLaunchKernelGGL(agg_kernel, dim3((NN + 3) / 4), dim3(256), 0, stream,
                       (const char*)p16, a_src, a_dst, src, row_ptr,
                       (float4*)d_out);
}

// Round 7
// 164.742 us; speedup vs baseline: 2.7609x; 1.0682x over previous
//
#include <hip/hip_runtime.h>
#include <hip/hip_fp16.h>
#include <math.h>

#define NN 100000
#define NE 1600000
#define DIM 64

__device__ __forceinline__ __half2 u2h2(unsigned u) { __half2 h; __builtin_memcpy(&h, &u, 4); return h; }
__device__ __forceinline__ unsigned h22u(__half2 h) { unsigned u; __builtin_memcpy(&u, &h, 4); return u; }
__device__ __forceinline__ unsigned pk_f16(float a, float b) {
    auto h = __builtin_amdgcn_cvt_pkrtz(a, b);   // one v_cvt_pkrtz_f16_f32
    unsigned u; __builtin_memcpy(&u, &h, 4); return u;
}

// ---------------------------------------------------------------------------
// Kernel 1: per-node projection  p = h @ W^T  (packed f16, rows [0,2NN)) and
// scalar a = p . w_attn. Rows [0,NN) = h_src, [NN,2NN) = h_dst.
// ---------------------------------------------------------------------------
#define WS 68   // padded LDS stride

__global__ __launch_bounds__(256) void proj_kernel(
    const float* __restrict__ h_src, const float* __restrict__ h_dst,
    const float* __restrict__ W, const float* __restrict__ w_attn,
    unsigned* __restrict__ p16, float* __restrict__ a_src, float* __restrict__ a_dst) {
    __shared__ __align__(16) float Wt[DIM * WS];
    __shared__ __align__(16) float Ht[DIM * WS];
    __shared__ __align__(16) float was[DIM];

    const int t = threadIdx.x;
    const int row0 = blockIdx.x * 64;

#pragma unroll
    for (int r = 0; r < 16; ++r) {
        int idx = r * 256 + t;
        int j = idx >> 6, k = idx & 63;
        Wt[k * WS + j] = W[idx];
    }
    if (t < DIM) was[t] = w_attn[t];

    {
        int k = t & 63;
        int nb = t >> 6;
#pragma unroll
        for (int r = 0; r < 16; ++r) {
            int nl = r * 4 + nb;
            int row = row0 + nl;
            const float* hp = (row < NN) ? (h_src + (size_t)row * DIM)
                                         : (h_dst + (size_t)(row - NN) * DIM);
            Ht[k * WS + nl] = hp[k];
        }
    }
    __syncthreads();

    const int jg = (t & 15) * 4;
    const int ng = (t >> 4) * 4;
    float acc[4][4];
#pragma unroll
    for (int a = 0; a < 4; ++a)
#pragma unroll
        for (int b = 0; b < 4; ++b) acc[a][b] = 0.f;

#pragma unroll 4
    for (int k = 0; k < DIM; ++k) {
        const float4 wv = *(const float4*)(Wt + k * WS + jg);
        const float4 hv = *(const float4*)(Ht + k * WS + ng);
        const float wa[4] = {wv.x, wv.y, wv.z, wv.w};
        const float ha[4] = {hv.x, hv.y, hv.z, hv.w};
#pragma unroll
        for (int a = 0; a < 4; ++a)
#pragma unroll
            for (int b = 0; b < 4; ++b) acc[a][b] += ha[a] * wa[b];
    }

    const float4 wat4 = *(const float4*)(was + jg);
#pragma unroll
    for (int a = 0; a < 4; ++a) {
        int row = row0 + ng + a;
        uint2 pk;
        pk.x = pk_f16(acc[a][0], acc[a][1]);
        pk.y = pk_f16(acc[a][2], acc[a][3]);
        *(uint2*)(p16 + (size_t)row * 32 + (jg >> 1)) = pk;

        float pa = acc[a][0] * wat4.x + acc[a][1] * wat4.y +
                   acc[a][2] * wat4.z + acc[a][3] * wat4.w;
#pragma unroll
        for (int off = 8; off; off >>= 1) pa += __shfl_xor(pa, off);
        if ((t & 15) == 0) {
            if (row < NN) a_src[row] = pa;
            else a_dst[row - NN] = pa;
        }
    }
}

// ---------------------------------------------------------------------------
// Kernel 2: CSR row_ptr from sorted dst (boundary scan).
// ---------------------------------------------------------------------------
__global__ void rowptr_kernel(const int* __restrict__ dst, int* __restrict__ row_ptr) {
    int i = blockIdx.x * blockDim.x + threadIdx.x;
    if (i >= NE) return;
    int d = dst[i];
    int prev = (i == 0) ? -1 : dst[i - 1];
    for (int n = prev + 1; n <= d; ++n) row_ptr[n] = i;
    if (i == NE - 1) {
        for (int n = d + 1; n <= NN; ++n) row_ptr[n] = NE;
    }
}

// ---------------------------------------------------------------------------
// Kernel 3: fused edge-score + segment softmax + aggregation + ELU.
// QUARTER-WAVE per node: 16 lanes per node, 4 nodes per wave, 16 per block.
// Staging: each group computes up to 16 edges' w = exp(tanh(ad - a_src[src]))
// in one pass (all 64 lanes of the wave productive), stages (w,w)|byte-offset
// in wave-private LDS. Gather: within a group, sub16=glane>>3 picks the edge,
// chunk=glane&7 picks a 16B piece of the 128B f16 row; 2-deep unroll -> 4
// edges/group/iter = 16/wave/iter (same VMEM throughput as before, 4x less
// per-node instruction overhead). Reductions: 4 shfl levels (s), 1 (acc).
// h_diff[n] = p_dst[n] - (sum_e w_e * p_src[src_e]) / s   (sum alpha = 1)
// ---------------------------------------------------------------------------
__global__ __launch_bounds__(256) void agg_kernel(
    const char* __restrict__ p16base,    // rows of 128B f16; [0,NN)=src, [NN,2NN)=dst
    const float* __restrict__ a_src, const float* __restrict__ a_dst,
    const int* __restrict__ src, const int* __restrict__ row_ptr,
    float4* __restrict__ out4) {
    __shared__ uint2 buf[4][64];
    const int wv = threadIdx.x >> 6;
    const int lane = threadIdx.x & 63;
    const int g = lane >> 4;            // group (node) within wave
    const int glane = lane & 15;        // lane within group
    const int sub16 = glane >> 3;       // which edge of a pair
    const int chunk = glane & 7;        // which 16B chunk of the 128B row

    const int wid = (blockIdx.x * 4 + wv) * 4 + g;
    if (wid >= NN) return;              // tail block only

    const int beg = row_ptr[wid];
    const int end = row_ptr[wid + 1];
    const bool nonempty = end > beg;

    const float ad = nonempty ? a_dst[wid] : 0.f;
    const char* pbase = p16base + (size_t)chunk * 16;
    uint2* bufw = buf[wv];
    const int gbase = g * 16;

    float sAcc = 0.f;
    __half2 acc[4];
#pragma unroll
    for (int q = 0; q < 4; ++q) acc[q] = u2h2(0u);

    for (int cb = beg; cb < end; cb += 16) {
        int cd = end - cb; if (cd > 16) cd = 16;
        uint2 pk = make_uint2(0u, 0u);
        float w = 0.f;
        if (glane < cd) {
            int sv = src[cb + glane];                  // ~coalesced (groups adjacent)
            float x = ad - a_src[sv];                  // 4B gather, L2-resident
            float th = 1.f - 2.f / (__expf(2.f * x) + 1.f);   // tanh
            w = __expf(th);
            pk.x = pk_f16(w, w);
            pk.y = (unsigned)sv * 128u;                // pre-scaled byte offset
        }
        sAcc += w;
        bufw[lane] = pk;                               // wave-private, no barrier

        for (int j = 0; j < cd; j += 4) {              // 4 edges/group/iter
            uint2 e0 = bufw[gbase + j + sub16];
            uint2 e1 = bufw[gbase + j + 2 + sub16];    // zero-filled beyond cd
            uint4 r0 = *(const uint4*)(pbase + e0.y);
            uint4 r1 = *(const uint4*)(pbase + e1.y);
            __half2 w0 = u2h2(e0.x), w1 = u2h2(e1.x);
            acc[0] = __hfma2(w0, u2h2(r0.x), acc[0]);
            acc[1] = __hfma2(w0, u2h2(r0.y), acc[1]);
            acc[2] = __hfma2(w0, u2h2(r0.z), acc[2]);
            acc[3] = __hfma2(w0, u2h2(r0.w), acc[3]);
            acc[0] = __hfma2(w1, u2h2(r1.x), acc[0]);
            acc[1] = __hfma2(w1, u2h2(r1.y), acc[1]);
            acc[2] = __hfma2(w1, u2h2(r1.z), acc[2]);
            acc[3] = __hfma2(w1, u2h2(r1.w), acc[3]);
        }
    }

    // s: reduce over the 16-lane group (levels 1,2,4,8 stay within group)
#pragma unroll
    for (int off = 1; off <= 8; off <<= 1) sAcc += __shfl_xor(sAcc, off);
    // acc: combine the two sub16 edge partitions (same channels)
#pragma unroll
    for (int q = 0; q < 4; ++q)
        acc[q] = __hadd2(acc[q], u2h2(__shfl_xor(h22u(acc[q]), 8)));

    if (sub16 == 0) {   // 8 lanes per group write the node's 64 channels
        const uint4 pdu = *(const uint4*)(p16base + ((size_t)(NN + wid)) * 128 + (size_t)chunk * 16);
        const unsigned pw[4] = {pdu.x, pdu.y, pdu.z, pdu.w};
        const float inv = nonempty ? 1.f / sAcc : 0.f;   // empty -> h = 0 -> elu = 0
        float o[8];
#pragma unroll
        for (int q = 0; q < 4; ++q) {
            float2 pf = __half22float2(u2h2(pw[q]));
            float2 af = __half22float2(acc[q]);
            float h0 = nonempty ? (pf.x - af.x * inv) : 0.f;
            float h1 = nonempty ? (pf.y - af.y * inv) : 0.f;
            o[2 * q]     = h0 > 0.f ? h0 : __expf(h0) - 1.f;
            o[2 * q + 1] = h1 > 0.f ? h1 : __expf(h1) - 1.f;
        }
        const size_t ob = (size_t)wid * 16 + chunk * 2;
        out4[ob]     = make_float4(o[0], o[1], o[2], o[3]);
        out4[ob + 1] = make_float4(o[4], o[5], o[6], o[7]);
    }
}

// ---------------------------------------------------------------------------
extern "C" void kernel_launch(void* const* d_in, const int* in_sizes, int n_in,
                              void* d_out, int out_size, void* d_ws, size_t ws_size,
                              hipStream_t stream) {
    const float* h_src = (const float*)d_in[0];
    const float* h_dst = (const float*)d_in[1];
    const float* W     = (const float*)d_in[2];
    const float* w_at  = (const float*)d_in[3];
    const int*   src   = (const int*)d_in[4];
    const int*   dst   = (const int*)d_in[5];

    char* ws = (char*)d_ws;
    unsigned* p16 = (unsigned*)ws;                        // 2NN*32 dwords = 25.6 MB
    float* a_src = (float*)(ws + (size_t)2 * NN * 32 * 4);
    float* a_dst = a_src + NN;
    int* row_ptr = (int*)(a_dst + NN);                    // NN+1

    hipLaunchKernelGGL(proj_kernel, dim3((2 * NN) / 64), dim3(256), 0, stream,
                       h_src, h_dst, W, w_at, p16, a_src, a_dst);
    hipLaunchKernelGGL(rowptr_kernel, dim3((NE + 255) / 256), dim3(256), 0, stream,
                       dst, row_ptr);
    hipLaunchKernelGGL(agg_kernel, dim3((NN + 15) / 16), dim3(256), 0, stream,
                       (const char*)p16, a_src, a_dst, src, row_ptr,
                       (float4*)d_out);
}

// Round 8
// 152.199 us; speedup vs baseline: 2.9885x; 1.0824x over previous
//
#include <hip/hip_runtime.h>
#include <hip/hip_fp16.h>
#include <math.h>

#define NN 100000
#define NE 1600000
#define DIM 64
#define HST 72   // proj LDS stride in halves (144B, 16B-aligned rows)

typedef __attribute__((ext_vector_type(8))) __fp16 half8;
typedef __attribute__((ext_vector_type(4))) float f32x4;

__device__ __forceinline__ __half2 u2h2(unsigned u) { __half2 h; __builtin_memcpy(&h, &u, 4); return h; }
__device__ __forceinline__ unsigned h22u(__half2 h) { unsigned u; __builtin_memcpy(&u, &h, 4); return u; }
__device__ __forceinline__ unsigned pk_f16(float a, float b) {
    auto h = __builtin_amdgcn_cvt_pkrtz(a, b);   // one v_cvt_pkrtz_f16_f32
    unsigned u; __builtin_memcpy(&u, &h, 4); return u;
}

// ---------------------------------------------------------------------------
// Kernel 1: per-node projection p = h @ W^T (f16 MFMA, f32 accumulate) and
// scalar a = p . w_attn. Rows [0,NN) = h_src, [NN,2NN) = h_dst.
// Block 256 = 4 waves, 64 rows/block. Wave wv owns rows m0=wv*16, computes
// 4 col-tiles x (K=64 as 2 x mfma_f32_16x16x32_f16). No transpose staging:
// A-frag = H rows, B-frag = W rows, both contiguous f16 in LDS.
// Fragment maps (HW-verified): A[m=lane&15][k=quad*8+j]; B[k][n=lane&15];
// C/D: col=lane&15, row=quad*4+reg.
// ---------------------------------------------------------------------------
__global__ __launch_bounds__(256) void proj_kernel(
    const float* __restrict__ h_src, const float* __restrict__ h_dst,
    const float* __restrict__ W, const float* __restrict__ w_attn,
    unsigned* __restrict__ p16, float* __restrict__ a_src, float* __restrict__ a_dst) {
    __shared__ __align__(16) unsigned short Hh[64 * HST];  // f16 bits
    __shared__ __align__(16) unsigned short Wh[64 * HST];
    __shared__ float was[DIM];

    const int t = threadIdx.x;
    const int row0 = blockIdx.x * 64;

    // Stage W (f32 -> f16), coalesced float4 reads, contiguous 8B LDS writes.
#pragma unroll
    for (int r = 0; r < 4; ++r) {
        int idx = (r * 256 + t) * 4;           // flat float index into 64x64 W
        int j = idx >> 6, k = idx & 63;
        float4 v = *(const float4*)(W + idx);
        uint2 pk; pk.x = pk_f16(v.x, v.y); pk.y = pk_f16(v.z, v.w);
        *(uint2*)((char*)Wh + j * (HST * 2) + k * 2) = pk;
    }
    if (t < DIM) was[t] = w_attn[t];

    // Stage H tile (row-major, no transpose).
#pragma unroll
    for (int r = 0; r < 4; ++r) {
        int idx = (r * 256 + t) * 4;
        int row = idx >> 6, k = idx & 63;
        int grow = row0 + row;
        const float* hp = (grow < NN) ? h_src + (size_t)grow * DIM
                                      : h_dst + (size_t)(grow - NN) * DIM;
        float4 v = *(const float4*)(hp + k);
        uint2 pk; pk.x = pk_f16(v.x, v.y); pk.y = pk_f16(v.z, v.w);
        *(uint2*)((char*)Hh + row * (HST * 2) + k * 2) = pk;
    }
    __syncthreads();

    const int wv = t >> 6, lane = t & 63;
    const int col = lane & 15, quad = lane >> 4;
    const int m0 = wv * 16;

    const char* Hb = (const char*)Hh + (m0 + col) * (HST * 2) + quad * 16;
    half8 af0 = *(const half8*)(Hb);           // k = quad*8+j, k0=0
    half8 af1 = *(const half8*)(Hb + 64);      // k0=32

    f32x4 c[4];
#pragma unroll
    for (int n = 0; n < 4; ++n) {
        const char* Bb = (const char*)Wh + (n * 16 + col) * (HST * 2) + quad * 16;
        half8 b0 = *(const half8*)(Bb);
        half8 b1 = *(const half8*)(Bb + 64);
        f32x4 acc = {0.f, 0.f, 0.f, 0.f};
        acc = __builtin_amdgcn_mfma_f32_16x16x32_f16(af0, b0, acc, 0, 0, 0);
        acc = __builtin_amdgcn_mfma_f32_16x16x32_f16(af1, b1, acc, 0, 0, 0);
        c[n] = acc;
    }

    // a = p . w_attn : per-lane partial over its 4 cols, reduce 16 cols in group.
    float wv4[4];
#pragma unroll
    for (int n = 0; n < 4; ++n) wv4[n] = was[n * 16 + col];
#pragma unroll
    for (int reg = 0; reg < 4; ++reg) {
        float pa = c[0][reg] * wv4[0] + c[1][reg] * wv4[1] +
                   c[2][reg] * wv4[2] + c[3][reg] * wv4[3];
#pragma unroll
        for (int off = 1; off <= 8; off <<= 1) pa += __shfl_xor(pa, off);
        if (col == 0) {
            int grow = row0 + m0 + quad * 4 + reg;
            if (grow < NN) a_src[grow] = pa;
            else a_dst[grow - NN] = pa;
        }
    }

    // Pack p to f16 dwords via LDS repack, then fully-coalesced dwordx4 store.
    __syncthreads();
    unsigned* Pd = (unsigned*)Hh;              // reuse: 64 rows x 32 dwords
#pragma unroll
    for (int n = 0; n < 4; ++n) {
#pragma unroll
        for (int reg = 0; reg < 4; ++reg) {
            float other = __shfl_xor(c[n][reg], 1);
            if (!(col & 1)) {
                unsigned pk = pk_f16(c[n][reg], other);
                Pd[(m0 + quad * 4 + reg) * 32 + (n * 16 + col) / 2] = pk;
            }
        }
    }
    __syncthreads();
#pragma unroll
    for (int r = 0; r < 2; ++r) {
        int idx = (r * 256 + t) * 4;           // dword index into 2048-dword tile
        uint4 v = *(const uint4*)(Pd + idx);
        *(uint4*)(p16 + (size_t)row0 * 32 + idx) = v;
    }
}

// ---------------------------------------------------------------------------
// Kernel 2: CSR row_ptr from sorted dst (boundary scan).
// ---------------------------------------------------------------------------
__global__ void rowptr_kernel(const int* __restrict__ dst, int* __restrict__ row_ptr) {
    int i = blockIdx.x * blockDim.x + threadIdx.x;
    if (i >= NE) return;
    int d = dst[i];
    int prev = (i == 0) ? -1 : dst[i - 1];
    for (int n = prev + 1; n <= d; ++n) row_ptr[n] = i;
    if (i == NE - 1) {
        for (int n = d + 1; n <= NN; ++n) row_ptr[n] = NE;
    }
}

// ---------------------------------------------------------------------------
// Kernel 3: fused edge-score + segment softmax + aggregation + ELU.
// Quarter-wave per node (16 lanes/node, 4 nodes/wave, 16/block). See R6 notes.
// h_diff[n] = p_dst[n] - (sum_e w_e * p_src[src_e]) / s   (sum alpha = 1)
// ---------------------------------------------------------------------------
__global__ __launch_bounds__(256) void agg_kernel(
    const char* __restrict__ p16base,    // rows of 128B f16; [0,NN)=src, [NN,2NN)=dst
    const float* __restrict__ a_src, const float* __restrict__ a_dst,
    const int* __restrict__ src, const int* __restrict__ row_ptr,
    float4* __restrict__ out4) {
    __shared__ uint2 buf[4][64];
    const int wv = threadIdx.x >> 6;
    const int lane = threadIdx.x & 63;
    const int g = lane >> 4;            // group (node) within wave
    const int glane = lane & 15;        // lane within group
    const int sub16 = glane >> 3;       // which edge of a pair
    const int chunk = glane & 7;        // which 16B chunk of the 128B row

    const int wid = (blockIdx.x * 4 + wv) * 4 + g;
    if (wid >= NN) return;

    const int beg = row_ptr[wid];
    const int end = row_ptr[wid + 1];
    const bool nonempty = end > beg;

    const float ad = nonempty ? a_dst[wid] : 0.f;
    const char* pbase = p16base + (size_t)chunk * 16;
    uint2* bufw = buf[wv];
    const int gbase = g * 16;

    float sAcc = 0.f;
    __half2 acc[4];
#pragma unroll
    for (int q = 0; q < 4; ++q) acc[q] = u2h2(0u);

    for (int cb = beg; cb < end; cb += 16) {
        int cd = end - cb; if (cd > 16) cd = 16;
        uint2 pk = make_uint2(0u, 0u);
        float w = 0.f;
        if (glane < cd) {
            int sv = src[cb + glane];                  // ~coalesced
            float x = ad - a_src[sv];                  // 4B gather, L2-resident
            float th = 1.f - 2.f / (__expf(2.f * x) + 1.f);   // tanh
            w = __expf(th);
            pk.x = pk_f16(w, w);
            pk.y = (unsigned)sv * 128u;                // pre-scaled byte offset
        }
        sAcc += w;
        bufw[lane] = pk;                               // wave-private, no barrier

        for (int j = 0; j < cd; j += 4) {              // 4 edges/group/iter
            uint2 e0 = bufw[gbase + j + sub16];
            uint2 e1 = bufw[gbase + j + 2 + sub16];    // zero-filled beyond cd
            uint4 r0 = *(const uint4*)(pbase + e0.y);
            uint4 r1 = *(const uint4*)(pbase + e1.y);
            __half2 w0 = u2h2(e0.x), w1 = u2h2(e1.x);
            acc[0] = __hfma2(w0, u2h2(r0.x), acc[0]);
            acc[1] = __hfma2(w0, u2h2(r0.y), acc[1]);
            acc[2] = __hfma2(w0, u2h2(r0.z), acc[2]);
            acc[3] = __hfma2(w0, u2h2(r0.w), acc[3]);
            acc[0] = __hfma2(w1, u2h2(r1.x), acc[0]);
            acc[1] = __hfma2(w1, u2h2(r1.y), acc[1]);
            acc[2] = __hfma2(w1, u2h2(r1.z), acc[2]);
            acc[3] = __hfma2(w1, u2h2(r1.w), acc[3]);
        }
    }

#pragma unroll
    for (int off = 1; off <= 8; off <<= 1) sAcc += __shfl_xor(sAcc, off);
#pragma unroll
    for (int q = 0; q < 4; ++q)
        acc[q] = __hadd2(acc[q], u2h2(__shfl_xor(h22u(acc[q]), 8)));

    if (sub16 == 0) {   // 8 lanes per group write the node's 64 channels
        const uint4 pdu = *(const uint4*)(p16base + ((size_t)(NN + wid)) * 128 + (size_t)chunk * 16);
        const unsigned pw[4] = {pdu.x, pdu.y, pdu.z, pdu.w};
        const float inv = nonempty ? 1.f / sAcc : 0.f;   // empty -> h = 0 -> elu = 0
        float o[8];
#pragma unroll
        for (int q = 0; q < 4; ++q) {
            float2 pf = __half22float2(u2h2(pw[q]));
            float2 af = __half22float2(acc[q]);
            float h0 = nonempty ? (pf.x - af.x * inv) : 0.f;
            float h1 = nonempty ? (pf.y - af.y * inv) : 0.f;
            o[2 * q]     = h0 > 0.f ? h0 : __expf(h0) - 1.f;
            o[2 * q + 1] = h1 > 0.f ? h1 : __expf(h1) - 1.f;
        }
        const size_t ob = (size_t)wid * 16 + chunk * 2;
        out4[ob]     = make_float4(o[0], o[1], o[2], o[3]);
        out4[ob + 1] = make_float4(o[4], o[5], o[6], o[7]);
    }
}

// ---------------------------------------------------------------------------
extern "C" void kernel_launch(void* const* d_in, const int* in_sizes, int n_in,
                              void* d_out, int out_size, void* d_ws, size_t ws_size,
                              hipStream_t stream) {
    const float* h_src = (const float*)d_in[0];
    const float* h_dst = (const float*)d_in[1];
    const float* W     = (const float*)d_in[2];
    const float* w_at  = (const float*)d_in[3];
    const int*   src   = (const int*)d_in[4];
    const int*   dst   = (const int*)d_in[5];

    char* ws = (char*)d_ws;
    unsigned* p16 = (unsigned*)ws;                        // 2NN*32 dwords = 25.6 MB
    float* a_src = (float*)(ws + (size_t)2 * NN * 32 * 4);
    float* a_dst = a_src + NN;
    int* row_ptr = (int*)(a_dst + NN);                    // NN+1

    hipLaunchKernelGGL(proj_kernel, dim3((2 * NN) / 64), dim3(256), 0, stream,
                       h_src, h_dst, W, w_at, p16, a_src, a_dst);
    hipLaunchKernelGGL(rowptr_kernel, dim3((NE + 255) / 256), dim3(256), 0, stream,
                       dst, row_ptr);
    hipLaunchKernelGGL(agg_kernel, dim3((NN + 15) / 16), dim3(256), 0, stream,
                       (const char*)p16, a_src, a_dst, src, row_ptr,
                       (float4*)d_out);
}

// Round 9
// 149.684 us; speedup vs baseline: 3.0387x; 1.0168x over previous
//
#include <hip/hip_runtime.h>
#include <hip/hip_fp16.h>
#include <math.h>

#define NN 100000
#define NE 1600000
#define DIM 64
#define HST 72   // proj LDS stride in halves (144B, 16B-aligned rows)
#define PROJ_BLOCKS ((2 * NN) / 64)          // 3125
#define ROWPTR_BLOCKS ((NE + 255) / 256)     // 6250

typedef __attribute__((ext_vector_type(8))) __fp16 half8;
typedef __attribute__((ext_vector_type(4))) float f32x4;

__device__ __forceinline__ __half2 u2h2(unsigned u) { __half2 h; __builtin_memcpy(&h, &u, 4); return h; }
__device__ __forceinline__ unsigned h22u(__half2 h) { unsigned u; __builtin_memcpy(&u, &h, 4); return u; }
__device__ __forceinline__ unsigned pk_f16(float a, float b) {
    auto h = __builtin_amdgcn_cvt_pkrtz(a, b);   // one v_cvt_pkrtz_f16_f32
    unsigned u; __builtin_memcpy(&u, &h, 4); return u;
}

// ---------------------------------------------------------------------------
// Kernel 1 (fused): blocks [0,PROJ_BLOCKS) do the MFMA projection
// p = h @ W^T (f16, f32-acc) + a = p.w_attn; blocks [PROJ_BLOCKS, +ROWPTR_BLOCKS)
// do the CSR row_ptr boundary scan. The two halves are independent (agg needs
// both) — fusing overlaps the BW-bound scan with the compute-bound proj.
// ---------------------------------------------------------------------------
__global__ __launch_bounds__(256) void proj_kernel(
    const float* __restrict__ h_src, const float* __restrict__ h_dst,
    const float* __restrict__ W, const float* __restrict__ w_attn,
    const int* __restrict__ dst, int* __restrict__ row_ptr,
    unsigned* __restrict__ p16, float* __restrict__ a_src, float* __restrict__ a_dst) {
    __shared__ __align__(16) unsigned short Hh[64 * HST];  // f16 bits
    __shared__ __align__(16) unsigned short Wh[64 * HST];
    __shared__ float was[DIM];

    const int t = threadIdx.x;

    if (blockIdx.x >= PROJ_BLOCKS) {
        // ---- rowptr part: boundary scan over sorted dst ----
        int i = (blockIdx.x - PROJ_BLOCKS) * 256 + t;
        if (i >= NE) return;
        int d = dst[i];
        int prev = (i == 0) ? -1 : dst[i - 1];
        for (int n = prev + 1; n <= d; ++n) row_ptr[n] = i;
        if (i == NE - 1) {
            for (int n = d + 1; n <= NN; ++n) row_ptr[n] = NE;
        }
        return;
    }

    const int row0 = blockIdx.x * 64;

    // Stage W (f32 -> f16), coalesced float4 reads, contiguous 8B LDS writes.
#pragma unroll
    for (int r = 0; r < 4; ++r) {
        int idx = (r * 256 + t) * 4;           // flat float index into 64x64 W
        int j = idx >> 6, k = idx & 63;
        float4 v = *(const float4*)(W + idx);
        uint2 pk; pk.x = pk_f16(v.x, v.y); pk.y = pk_f16(v.z, v.w);
        *(uint2*)((char*)Wh + j * (HST * 2) + k * 2) = pk;
    }
    if (t < DIM) was[t] = w_attn[t];

    // Stage H tile (row-major, no transpose).
#pragma unroll
    for (int r = 0; r < 4; ++r) {
        int idx = (r * 256 + t) * 4;
        int row = idx >> 6, k = idx & 63;
        int grow = row0 + row;
        const float* hp = (grow < NN) ? h_src + (size_t)grow * DIM
                                      : h_dst + (size_t)(grow - NN) * DIM;
        float4 v = *(const float4*)(hp + k);
        uint2 pk; pk.x = pk_f16(v.x, v.y); pk.y = pk_f16(v.z, v.w);
        *(uint2*)((char*)Hh + row * (HST * 2) + k * 2) = pk;
    }
    __syncthreads();

    const int wv = t >> 6, lane = t & 63;
    const int col = lane & 15, quad = lane >> 4;
    const int m0 = wv * 16;

    const char* Hb = (const char*)Hh + (m0 + col) * (HST * 2) + quad * 16;
    half8 af0 = *(const half8*)(Hb);           // k = quad*8+j, k0=0
    half8 af1 = *(const half8*)(Hb + 64);      // k0=32

    f32x4 c[4];
#pragma unroll
    for (int n = 0; n < 4; ++n) {
        const char* Bb = (const char*)Wh + (n * 16 + col) * (HST * 2) + quad * 16;
        half8 b0 = *(const half8*)(Bb);
        half8 b1 = *(const half8*)(Bb + 64);
        f32x4 acc = {0.f, 0.f, 0.f, 0.f};
        acc = __builtin_amdgcn_mfma_f32_16x16x32_f16(af0, b0, acc, 0, 0, 0);
        acc = __builtin_amdgcn_mfma_f32_16x16x32_f16(af1, b1, acc, 0, 0, 0);
        c[n] = acc;
    }

    // a = p . w_attn : per-lane partial over its 4 cols, reduce 16 cols in group.
    float wv4[4];
#pragma unroll
    for (int n = 0; n < 4; ++n) wv4[n] = was[n * 16 + col];
#pragma unroll
    for (int reg = 0; reg < 4; ++reg) {
        float pa = c[0][reg] * wv4[0] + c[1][reg] * wv4[1] +
                   c[2][reg] * wv4[2] + c[3][reg] * wv4[3];
#pragma unroll
        for (int off = 1; off <= 8; off <<= 1) pa += __shfl_xor(pa, off);
        if (col == 0) {
            int grow = row0 + m0 + quad * 4 + reg;
            if (grow < NN) a_src[grow] = pa;
            else a_dst[grow - NN] = pa;
        }
    }

    // Pack p to f16 dwords via LDS repack, then fully-coalesced dwordx4 store.
    __syncthreads();
    unsigned* Pd = (unsigned*)Hh;              // reuse: 64 rows x 32 dwords
#pragma unroll
    for (int n = 0; n < 4; ++n) {
#pragma unroll
        for (int reg = 0; reg < 4; ++reg) {
            float other = __shfl_xor(c[n][reg], 1);
            if (!(col & 1)) {
                unsigned pk = pk_f16(c[n][reg], other);
                Pd[(m0 + quad * 4 + reg) * 32 + (n * 16 + col) / 2] = pk;
            }
        }
    }
    __syncthreads();
#pragma unroll
    for (int r = 0; r < 2; ++r) {
        int idx = (r * 256 + t) * 4;           // dword index into 2048-dword tile
        uint4 v = *(const uint4*)(Pd + idx);
        *(uint4*)(p16 + (size_t)row0 * 32 + idx) = v;
    }
}

// ---------------------------------------------------------------------------
// Kernel 2: fused edge-score + segment softmax + aggregation + ELU.
// Quarter-wave per node (16 lanes/node, 4 nodes/wave, 16/block).
// Fast path for full 16-edge chunks: 8 LDS entry reads then 8 independent
// dwordx4 gathers in flight (4x the MLP of the 2-deep loop).
// h_diff[n] = p_dst[n] - (sum_e w_e * p_src[src_e]) / s   (sum alpha = 1)
// ---------------------------------------------------------------------------
__global__ __launch_bounds__(256) void agg_kernel(
    const char* __restrict__ p16base,    // rows of 128B f16; [0,NN)=src, [NN,2NN)=dst
    const float* __restrict__ a_src, const float* __restrict__ a_dst,
    const int* __restrict__ src, const int* __restrict__ row_ptr,
    float4* __restrict__ out4) {
    __shared__ uint2 buf[4][64];
    const int wv = threadIdx.x >> 6;
    const int lane = threadIdx.x & 63;
    const int g = lane >> 4;            // group (node) within wave
    const int glane = lane & 15;        // lane within group
    const int sub16 = glane >> 3;       // which edge of a pair
    const int chunk = glane & 7;        // which 16B chunk of the 128B row

    const int wid = (blockIdx.x * 4 + wv) * 4 + g;
    if (wid >= NN) return;

    const int beg = row_ptr[wid];
    const int end = row_ptr[wid + 1];
    const bool nonempty = end > beg;

    if (!nonempty) {
        if (sub16 == 0) {
            const size_t ob = (size_t)wid * 16 + chunk * 2;
            out4[ob]     = make_float4(0.f, 0.f, 0.f, 0.f);
            out4[ob + 1] = make_float4(0.f, 0.f, 0.f, 0.f);
        }
        return;
    }

    // prefetch p_dst row chunk early (overlaps the edge loop)
    const uint4 pdu = *(const uint4*)(p16base + ((size_t)(NN + wid)) * 128 + (size_t)chunk * 16);

    const float ad = a_dst[wid];
    const char* pbase = p16base + (size_t)chunk * 16;
    uint2* bufw = buf[wv];
    const int gbase = g * 16;

    float sAcc = 0.f;
    __half2 acc[4];
#pragma unroll
    for (int q = 0; q < 4; ++q) acc[q] = u2h2(0u);

    for (int cb = beg; cb < end; cb += 16) {
        int cd = end - cb; if (cd > 16) cd = 16;
        uint2 pk = make_uint2(0u, 0u);
        float w = 0.f;
        if (glane < cd) {
            int sv = src[cb + glane];                  // ~coalesced
            float x = ad - a_src[sv];                  // 4B gather, L2-resident
            float th = 1.f - 2.f / (__expf(2.f * x) + 1.f);   // tanh
            w = __expf(th);
            pk.x = pk_f16(w, w);
            pk.y = (unsigned)sv * 128u;                // pre-scaled byte offset
        }
        sAcc += w;
        bufw[lane] = pk;                               // wave-private, no barrier

        if (cd == 16) {
            // fast path: 8 gathers in flight per lane (16 edges/group)
            uint2 e[8];
#pragma unroll
            for (int q = 0; q < 8; ++q) e[q] = bufw[gbase + 2 * q + sub16];
            uint4 r[8];
#pragma unroll
            for (int q = 0; q < 8; ++q) r[q] = *(const uint4*)(pbase + e[q].y);
#pragma unroll
            for (int q = 0; q < 8; ++q) {
                __half2 wq = u2h2(e[q].x);
                acc[0] = __hfma2(wq, u2h2(r[q].x), acc[0]);
                acc[1] = __hfma2(wq, u2h2(r[q].y), acc[1]);
                acc[2] = __hfma2(wq, u2h2(r[q].z), acc[2]);
                acc[3] = __hfma2(wq, u2h2(r[q].w), acc[3]);
            }
        } else {
            for (int j = 0; j < cd; j += 4) {          // 4 edges/group/iter
                uint2 e0 = bufw[gbase + j + sub16];
                uint2 e1 = bufw[gbase + j + 2 + sub16];    // zero-filled beyond cd
                uint4 r0 = *(const uint4*)(pbase + e0.y);
                uint4 r1 = *(const uint4*)(pbase + e1.y);
                __half2 w0 = u2h2(e0.x), w1 = u2h2(e1.x);
                acc[0] = __hfma2(w0, u2h2(r0.x), acc[0]);
                acc[1] = __hfma2(w0, u2h2(r0.y), acc[1]);
                acc[2] = __hfma2(w0, u2h2(r0.z), acc[2]);
                acc[3] = __hfma2(w0, u2h2(r0.w), acc[3]);
                acc[0] = __hfma2(w1, u2h2(r1.x), acc[0]);
                acc[1] = __hfma2(w1, u2h2(r1.y), acc[1]);
                acc[2] = __hfma2(w1, u2h2(r1.z), acc[2]);
                acc[3] = __hfma2(w1, u2h2(r1.w), acc[3]);
            }
        }
    }

#pragma unroll
    for (int off = 1; off <= 8; off <<= 1) sAcc += __shfl_xor(sAcc, off);
#pragma unroll
    for (int q = 0; q < 4; ++q)
        acc[q] = __hadd2(acc[q], u2h2(__shfl_xor(h22u(acc[q]), 8)));

    if (sub16 == 0) {   // 8 lanes per group write the node's 64 channels
        const unsigned pw[4] = {pdu.x, pdu.y, pdu.z, pdu.w};
        const float inv = 1.f / sAcc;
        float o[8];
#pragma unroll
        for (int q = 0; q < 4; ++q) {
            float2 pf = __half22float2(u2h2(pw[q]));
            float2 af = __half22float2(acc[q]);
            float h0 = pf.x - af.x * inv;
            float h1 = pf.y - af.y * inv;
            o[2 * q]     = h0 > 0.f ? h0 : __expf(h0) - 1.f;
            o[2 * q + 1] = h1 > 0.f ? h1 : __expf(h1) - 1.f;
        }
        const size_t ob = (size_t)wid * 16 + chunk * 2;
        out4[ob]     = make_float4(o[0], o[1], o[2], o[3]);
        out4[ob + 1] = make_float4(o[4], o[5], o[6], o[7]);
    }
}

// ---------------------------------------------------------------------------
extern "C" void kernel_launch(void* const* d_in, const int* in_sizes, int n_in,
                              void* d_out, int out_size, void* d_ws, size_t ws_size,
                              hipStream_t stream) {
    const float* h_src = (const float*)d_in[0];
    const float* h_dst = (const float*)d_in[1];
    const float* W     = (const float*)d_in[2];
    const float* w_at  = (const float*)d_in[3];
    const int*   src   = (const int*)d_in[4];
    const int*   dst   = (const int*)d_in[5];

    char* ws = (char*)d_ws;
    unsigned* p16 = (unsigned*)ws;                        // 2NN*32 dwords = 25.6 MB
    float* a_src = (float*)(ws + (size_t)2 * NN * 32 * 4);
    float* a_dst = a_src + NN;
    int* row_ptr = (int*)(a_dst + NN);                    // NN+1

    hipLaunchKernelGGL(proj_kernel, dim3(PROJ_BLOCKS + ROWPTR_BLOCKS), dim3(256), 0, stream,
                       h_src, h_dst, W, w_at, dst, row_ptr, p16, a_src, a_dst);
    hipLaunchKernelGGL(agg_kernel, dim3((NN + 15) / 16), dim3(256), 0, stream,
                       (const char*)p16, a_src, a_dst, src, row_ptr,
                       (float4*)d_out);
}